// Round 9
// baseline (177.262 us; speedup 1.0000x reference)
//
#include <hip/hip_runtime.h>
#include <math.h>

typedef unsigned short u16;
typedef __bf16 bf16x8 __attribute__((ext_vector_type(8)));
typedef float floatx4 __attribute__((ext_vector_type(4)));

#define S_LEN 2048
#define NBATCH 4

__device__ __forceinline__ u16 f2bf(float f) {
  union { float f; unsigned u; } v; v.f = f;
  unsigned r = v.u + 0x7FFFu + ((v.u >> 16) & 1u);
  return (u16)(r >> 16);
}

__device__ __forceinline__ void gload_lds16(const void* g, void* l) {
  __builtin_amdgcn_global_load_lds(
      (__attribute__((address_space(1))) const void*)g,
      (__attribute__((address_space(3))) void*)l, 16, 0, 0);
}

// ---------------- convert x (fp32 -> bf16), vectorized ----------------
__global__ __launch_bounds__(256) void convert_x_kernel(const float4* __restrict__ x4,
                                                        u16* __restrict__ xb) {
  int i = blockIdx.x * 256 + threadIdx.x;   // n4 = 2,097,152 exactly
  float4 v = x4[i];
  ushort4 o;
  o.x = f2bf(v.x); o.y = f2bf(v.y); o.z = f2bf(v.z); o.w = f2bf(v.w);
  ((ushort4*)xb)[i] = o;
}

// ------------- transpose + convert weights: Wt[w][e][d] = bf16(W_w[d][e]) -------------
__global__ __launch_bounds__(256) void transpose_w_kernel(const float* __restrict__ Wq,
                                                          const float* __restrict__ Wk,
                                                          const float* __restrict__ Wv,
                                                          u16* __restrict__ Wt) {
  int w = blockIdx.z;
  const float* W = (w == 0) ? Wq : ((w == 1) ? Wk : Wv);
  u16* T = Wt + (size_t)w * 1048576;
  __shared__ float tile[32][33];
  int e0 = blockIdx.x * 32, d0 = blockIdx.y * 32;
  int tx = threadIdx.x, ty = threadIdx.y;   // block (32,8)
#pragma unroll
  for (int j = ty; j < 32; j += 8)
    tile[j][tx] = W[(size_t)(d0 + j) * 1024 + e0 + tx];
  __syncthreads();
#pragma unroll
  for (int j = ty; j < 32; j += 8)
    T[(size_t)(e0 + j) * 1024 + d0 + tx] = f2bf(tile[tx][j]);
}

// ---------------- core C = A * B^T (proven 2-phase 128x128, BK=64) ----------------
// EPI epilogues: 1 = bf16 store (proj);
//   2 = scores: p=exp(acc*scale) bf16, diag mask col>row -> 0, atomic row sums;
//   3 = PV direct: fp32 store * (1/sums[row]);
//   4 = raw fp32 store (PV split-K partial; mC0 re-bases the C row origin).
template <int EPI, int BM>
__device__ __forceinline__ void gemm_core(
    const u16* __restrict__ A, const u16* __restrict__ B, void* __restrict__ Cv,
    int m0, int n0, int lda, int ldb, int ldc, int Keff, float scale,
    float* __restrict__ sums, int diag, int mC0) {
  constexpr int ABYTES = BM * 128;
  constexpr int AJ = BM / 32;
  constexpr int MFR = BM / 32;
  constexpr int HALF = ABYTES + 16384;

  __shared__ u16 lds_t[2 * (BM * 64 + 128 * 64)];
  char* ldsc = (char*)lds_t;

  const int t = threadIdx.x, wave = t >> 6, lane = t & 63;

  const char* pA[AJ]; char* dA[AJ];
  const char* pB[4];  char* dB[4];
#pragma unroll
  for (int j = 0; j < AJ; ++j) {
    int o = (j * 4 + wave) * 1024 + lane * 16;
    int g = o ^ (((o >> 7) & 7) << 4);
    int row = g >> 7, colb = g & 127;
    pA[j] = (const char*)A + ((size_t)(m0 + row) * lda) * 2 + colb;
    dA[j] = ldsc + (j * 4 + wave) * 1024;
  }
#pragma unroll
  for (int j = 0; j < 4; ++j) {
    int o = (j * 4 + wave) * 1024 + lane * 16;
    int g = o ^ (((o >> 7) & 7) << 4);
    int row = g >> 7, colb = g & 127;
    pB[j] = (const char*)B + ((size_t)(n0 + row) * ldb) * 2 + colb;
    dB[j] = ldsc + ABYTES + (j * 4 + wave) * 1024;
  }

  auto STAGE = [&](int buf, int k0) {
    const int bo = buf * HALF;
#pragma unroll
    for (int j = 0; j < AJ; ++j) gload_lds16(pA[j] + (size_t)k0 * 2, dA[j] + bo);
#pragma unroll
    for (int j = 0; j < 4;  ++j) gload_lds16(pB[j] + (size_t)k0 * 2, dB[j] + bo);
  };

  const int wm = wave >> 1, wn = wave & 1;
  const int ra0 = wm * (BM / 2) + (lane & 15);
  const int rb0 = wn * 64 + (lane & 15);
  const int cb0 = (lane >> 4) * 16;

  floatx4 acc[MFR][4];
#pragma unroll
  for (int i = 0; i < MFR; ++i)
#pragma unroll
    for (int j = 0; j < 4; ++j) acc[i][j] = (floatx4){0.f, 0.f, 0.f, 0.f};

  STAGE(0, 0);
  int cur = 0;
  for (int k0 = 0; k0 < Keff; k0 += 64) {
    const int kn = k0 + 64;
    if (kn < Keff) {
      STAGE(cur ^ 1, kn);
      if constexpr (AJ + 4 == 6) asm volatile("s_waitcnt vmcnt(6)" ::: "memory");
      else                       asm volatile("s_waitcnt vmcnt(8)" ::: "memory");
    } else {
      asm volatile("s_waitcnt vmcnt(0)" ::: "memory");
    }
    __builtin_amdgcn_s_barrier();
    __builtin_amdgcn_sched_barrier(0);

    const int bo = cur * HALF;
    bf16x8 af[2][MFR], bfv[2][4];
#pragma unroll
    for (int kk = 0; kk < 2; ++kk) {
#pragma unroll
      for (int f = 0; f < MFR; ++f) {
        int rA = ra0 + f * 16;
        int oA = rA * 128 + kk * 64 + cb0; oA ^= ((rA & 7) << 4);
        af[kk][f] = *(const bf16x8*)(ldsc + bo + oA);
      }
#pragma unroll
      for (int f = 0; f < 4; ++f) {
        int rB = rb0 + f * 16;
        int oB = rB * 128 + kk * 64 + cb0; oB ^= ((rB & 7) << 4);
        bfv[kk][f] = *(const bf16x8*)(ldsc + bo + ABYTES + oB);
      }
    }
    __builtin_amdgcn_s_setprio(1);
#pragma unroll
    for (int kk = 0; kk < 2; ++kk)
#pragma unroll
      for (int mI = 0; mI < MFR; ++mI)
#pragma unroll
        for (int nI = 0; nI < 4; ++nI)
          acc[mI][nI] = __builtin_amdgcn_mfma_f32_16x16x32_bf16(
              af[kk][mI], bfv[kk][nI], acc[mI][nI], 0, 0, 0);
    __builtin_amdgcn_s_setprio(0);

    __builtin_amdgcn_sched_barrier(0);
    __builtin_amdgcn_s_barrier();
    cur ^= 1;
  }

  const int crow0 = mC0 + wm * (BM / 2) + ((lane >> 4) * 4);
  const int ccol0 = n0 + wn * 64 + (lane & 15);
  if constexpr (EPI == 1) {
    u16* C = (u16*)Cv;
#pragma unroll
    for (int mI = 0; mI < MFR; ++mI)
#pragma unroll
      for (int r = 0; r < 4; ++r) {
        size_t ro = (size_t)(crow0 + mI * 16 + r) * ldc + ccol0;
#pragma unroll
        for (int nI = 0; nI < 4; ++nI)
          C[ro + nI * 16] = f2bf(acc[mI][nI][r] * scale);
      }
  } else if constexpr (EPI == 2) {
    u16* C = (u16*)Cv;
#pragma unroll
    for (int mI = 0; mI < MFR; ++mI)
#pragma unroll
      for (int r = 0; r < 4; ++r) {
        const int row = crow0 + mI * 16 + r;
        size_t ro = (size_t)row * ldc + ccol0;
        float ls = 0.f;
#pragma unroll
        for (int nI = 0; nI < 4; ++nI) {
          const int col = ccol0 + nI * 16;
          float p = __expf(acc[mI][nI][r] * scale);
          if (diag && col > row) p = 0.f;
          C[ro + nI * 16] = f2bf(p);
          ls += p;
        }
        ls += __shfl_xor(ls, 1); ls += __shfl_xor(ls, 2);
        ls += __shfl_xor(ls, 4); ls += __shfl_xor(ls, 8);
        if ((lane & 15) == 0) atomicAdd(&sums[row], ls);
      }
  } else if constexpr (EPI == 3) {
    float* C = (float*)Cv;
#pragma unroll
    for (int mI = 0; mI < MFR; ++mI)
#pragma unroll
      for (int r = 0; r < 4; ++r) {
        const int row = crow0 + mI * 16 + r;
        const float inv = 1.0f / sums[row];
        size_t ro = (size_t)row * ldc + ccol0;
#pragma unroll
        for (int nI = 0; nI < 4; ++nI)
          C[ro + nI * 16] = acc[mI][nI][r] * inv;
      }
  } else {
    float* C = (float*)Cv;
#pragma unroll
    for (int mI = 0; mI < MFR; ++mI)
#pragma unroll
      for (int r = 0; r < 4; ++r) {
        size_t ro = (size_t)(crow0 + mI * 16 + r) * ldc + ccol0;
#pragma unroll
        for (int nI = 0; nI < 4; ++nI)
          C[ro + nI * 16] = acc[mI][nI][r];
      }
  }
}

// ---------------- merged projections (round-8 proven, XCD-chunked) ----------------
__global__ __launch_bounds__(256) void proj_fused(const u16* __restrict__ xb,
                                                  const u16* __restrict__ Wt,
                                                  u16* __restrict__ qk,
                                                  u16* __restrict__ vt) {
  const int id = blockIdx.y * 16 + blockIdx.x;
  const int lin = (id & 7) * 192 + (id >> 3);        // bijective XCD chunking
  const int bx = lin & 15, by = lin >> 4;
  const u16 *A, *B; u16* C; int m0, n0, ldc;
  if (by < 64) {
    A = xb; B = Wt; C = qk;
    m0 = by * 128; n0 = bx * 128; ldc = 2048;
  } else {
    int idx = (by - 64) * 16 + bx;                   // [0,512)
    A = Wt + 2097152; B = xb; C = vt;
    m0 = (idx & 7) * 128; n0 = (idx >> 3) * 128; ldc = 8192;
  }
  gemm_core<1, 128>(A, B, C, m0, n0, 1024, 1024, ldc, 1024, 1.0f, nullptr, 0, m0);
}

// ---------------- scores: P~ = exp(q k^T / 32) bf16 + atomic row sums ----------------
// Grid 544 = exactly the causal tiles; triangular-packed, XCD-chunked (8 x 68).
__global__ __launch_bounds__(256) void gemm_scores(const u16* __restrict__ qk,
                                                   u16* __restrict__ sc16,
                                                   float* __restrict__ sums) {
  const int lin = blockIdx.x;
  const int g = (lin & 7) * 68 + (lin >> 3);         // bijective: 544 = 8*68
  const int z = g / 136, t = g - z * 136;
  int bi = (int)((sqrtf(8.f * (float)t + 1.f) - 1.f) * 0.5f);
  while ((bi + 1) * (bi + 2) / 2 <= t) ++bi;
  while (bi * (bi + 1) / 2 > t) --bi;
  const int bj = t - bi * (bi + 1) / 2;
  const u16* base = qk + (size_t)z * 4194304;
  gemm_core<2, 128>(base, base + 1024, sc16 + (size_t)z * 4194304,
                    bi * 128, bj * 128, 2048, 2048, 2048, 1024, 0.03125f,
                    sums + z * 2048, (bi == bj) ? 1 : 0, bi * 128);
}

// ---------------- PV with split-K for bi>=8 ----------------
// y in [0,24): y<8 -> c1 chunk of bi=15-y (raw -> part, rows re-based -1024);
// y in [8,16) -> c0 chunk of bi=23-y (raw -> out); y>=16 -> full bi=23-y (scaled -> out).
__global__ __launch_bounds__(256) void gemm_pv(const u16* __restrict__ sc16,
                                               const u16* __restrict__ vt,
                                               float* __restrict__ out,
                                               float* __restrict__ part,
                                               float* __restrict__ sums) {
  const int bj = blockIdx.x, z = blockIdx.z, y = blockIdx.y;
  int bi, ks, kl, mode;
  if (y < 8)       { bi = 15 - y; kl = (bi + 1) >> 1; ks = (bi + 1) - kl; mode = 2; }
  else if (y < 16) { bi = 23 - y; ks = 0; kl = (bi + 2) >> 1; mode = 1; }
  else             { bi = 23 - y; ks = 0; kl = bi + 1; mode = 0; }
  const u16* A = sc16 + (size_t)z * 4194304 + ks * 128;
  const u16* B = vt + (size_t)z * 2048 + ks * 128;
  float* outz = out + (size_t)z * 2097152;
  if (mode == 0) {
    gemm_core<3, 128>(A, B, outz, bi * 128, bj * 128, 2048, 8192, 1024,
                      kl * 128, 1.0f, sums + z * 2048, 0, bi * 128);
  } else {
    float* Cp = (mode == 1) ? outz : part + (size_t)z * 1048576;
    int mc = (mode == 1) ? bi * 128 : bi * 128 - 1024;
    gemm_core<4, 128>(A, B, Cp, bi * 128, bj * 128, 2048, 8192, 1024,
                      kl * 128, 1.0f, nullptr, 0, mc);
  }
}

// ---------------- combine: rows 1024..2047: out = (out + part) / rowsum ----------------
__global__ __launch_bounds__(256) void pv_combine(float* __restrict__ out,
                                                  const float* __restrict__ part,
                                                  const float* __restrict__ sums) {
  const int z = blockIdx.y, r = blockIdx.x;          // r in [0,1024)
  const int row = 1024 + r;
  const float inv = 1.0f / sums[z * 2048 + row];
  float4* o4 = (float4*)(out + (size_t)z * 2097152 + (size_t)row * 1024);
  const float4* p4 = (const float4*)(part + (size_t)z * 1048576 + (size_t)r * 1024);
  const int i = threadIdx.x;                         // 256 float4 = 1024 floats
  float4 a = o4[i]; float4 b = p4[i];
  a.x = (a.x + b.x) * inv; a.y = (a.y + b.y) * inv;
  a.z = (a.z + b.z) * inv; a.w = (a.w + b.w) * inv;
  o4[i] = a;
}

// ---------------- launch ----------------
extern "C" void kernel_launch(void* const* d_in, const int* in_sizes, int n_in,
                              void* d_out, int out_size, void* d_ws, size_t ws_size,
                              hipStream_t stream) {
  const float* x  = (const float*)d_in[0];
  const float* Wq = (const float*)d_in[1];
  const float* Wk = (const float*)d_in[2];
  const float* Wv = (const float*)d_in[3];
  float* out = (float*)d_out;
  char* ws = (char*)d_ws;

  const size_t MB = 1ull << 20;
  u16*  xb   = (u16*)(ws);              // 16 MiB : x bf16           [8192][1024]
  u16*  Wt   = (u16*)(ws + 16 * MB);    //  6 MiB : Wq^T|Wk^T|Wv^T   [3][1024][1024]
  u16*  qk   = (u16*)(ws + 22 * MB);    // 32 MiB : [q|k] bf16       [4*2048][2048]
  u16*  vt   = (u16*)(ws + 54 * MB);    // 16 MiB : v^T bf16         [1024][8192]
  u16*  sc16 = (u16*)(ws + 70 * MB);    // 32 MiB : P~ bf16          [4][2048][2048]
  float* part = (float*)(ws + 102 * MB); // 16 MiB : PV c1 partial   [4][1024][1024]
  float* sums = (float*)(ws + 118 * MB); // 32 KiB : row sums        [4][2048]

  hipMemsetAsync(sums, 0, NBATCH * 2048 * sizeof(float), stream);

  convert_x_kernel<<<8192, 256, 0, stream>>>((const float4*)x, xb);
  transpose_w_kernel<<<dim3(32, 32, 3), dim3(32, 8), 0, stream>>>(Wq, Wk, Wv, Wt);

  // all projections in one dispatch: 1536 blocks, XCD-chunked
  proj_fused<<<dim3(16, 96), 256, 0, stream>>>(xb, Wt, qk, vt);

  // P~ = exp(q k^T / 32) bf16 + row sums : 544 blocks exact
  gemm_scores<<<544, 256, 0, stream>>>(qk, sc16, sums);

  // out = P~ V / rowsum; split-K for bi>=8 : 768 blocks
  gemm_pv<<<dim3(8, 24, 4), 256, 0, stream>>>(sc16, vt, out, part, sums);

  // combine split rows
  pv_combine<<<dim3(1024, 4), 256, 0, stream>>>(out, part, sums);
}

// Round 10
// 161.977 us; speedup vs baseline: 1.0944x; 1.0944x over previous
//
#include <hip/hip_runtime.h>
#include <math.h>

typedef unsigned short u16;
typedef __bf16 bf16x8 __attribute__((ext_vector_type(8)));
typedef float floatx4 __attribute__((ext_vector_type(4)));

#define S_LEN 2048
#define NBATCH 4

__device__ __forceinline__ u16 f2bf(float f) {
  union { float f; unsigned u; } v; v.f = f;
  unsigned r = v.u + 0x7FFFu + ((v.u >> 16) & 1u);
  return (u16)(r >> 16);
}

__device__ __forceinline__ void gload_lds16(const void* g, void* l) {
  __builtin_amdgcn_global_load_lds(
      (__attribute__((address_space(1))) const void*)g,
      (__attribute__((address_space(3))) void*)l, 16, 0, 0);
}

// ---------------- convert x (fp32 -> bf16), vectorized ----------------
__global__ __launch_bounds__(256) void convert_x_kernel(const float4* __restrict__ x4,
                                                        u16* __restrict__ xb) {
  int i = blockIdx.x * 256 + threadIdx.x;   // n4 = 2,097,152 exactly
  float4 v = x4[i];
  ushort4 o;
  o.x = f2bf(v.x); o.y = f2bf(v.y); o.z = f2bf(v.z); o.w = f2bf(v.w);
  ((ushort4*)xb)[i] = o;
}

// ------------- transpose + convert weights: Wt[w][e][d] = bf16(W_w[d][e]) -------------
__global__ __launch_bounds__(256) void transpose_w_kernel(const float* __restrict__ Wq,
                                                          const float* __restrict__ Wk,
                                                          const float* __restrict__ Wv,
                                                          u16* __restrict__ Wt) {
  int w = blockIdx.z;
  const float* W = (w == 0) ? Wq : ((w == 1) ? Wk : Wv);
  u16* T = Wt + (size_t)w * 1048576;
  __shared__ float tile[32][33];
  int e0 = blockIdx.x * 32, d0 = blockIdx.y * 32;
  int tx = threadIdx.x, ty = threadIdx.y;   // block (32,8)
#pragma unroll
  for (int j = ty; j < 32; j += 8)
    tile[j][tx] = W[(size_t)(d0 + j) * 1024 + e0 + tx];
  __syncthreads();
#pragma unroll
  for (int j = ty; j < 32; j += 8)
    T[(size_t)(e0 + j) * 1024 + d0 + tx] = f2bf(tile[tx][j]);
}

// ---------------- core C = A * B^T (proven 2-phase 128x128, BK=64) ----------------
// EPI epilogues: 1 = bf16 store (proj);
//   2 = scores: p=exp(acc*scale) bf16, diag mask col>row -> 0, atomic row sums;
//   3 = PV fp32 store, scaled by 1/sums[row] when sums != nullptr (runtime),
//       raw when sums == nullptr. ONE instantiation per kernel (LDS budget!).
template <int EPI, int BM>
__device__ __forceinline__ void gemm_core(
    const u16* __restrict__ A, const u16* __restrict__ B, void* __restrict__ Cv,
    int m0, int n0, int lda, int ldb, int ldc, int Keff, float scale,
    float* __restrict__ sums, int diag, int mC0) {
  constexpr int ABYTES = BM * 128;
  constexpr int AJ = BM / 32;
  constexpr int MFR = BM / 32;
  constexpr int HALF = ABYTES + 16384;

  __shared__ u16 lds_t[2 * (BM * 64 + 128 * 64)];
  char* ldsc = (char*)lds_t;

  const int t = threadIdx.x, wave = t >> 6, lane = t & 63;

  const char* pA[AJ]; char* dA[AJ];
  const char* pB[4];  char* dB[4];
#pragma unroll
  for (int j = 0; j < AJ; ++j) {
    int o = (j * 4 + wave) * 1024 + lane * 16;
    int g = o ^ (((o >> 7) & 7) << 4);
    int row = g >> 7, colb = g & 127;
    pA[j] = (const char*)A + ((size_t)(m0 + row) * lda) * 2 + colb;
    dA[j] = ldsc + (j * 4 + wave) * 1024;
  }
#pragma unroll
  for (int j = 0; j < 4; ++j) {
    int o = (j * 4 + wave) * 1024 + lane * 16;
    int g = o ^ (((o >> 7) & 7) << 4);
    int row = g >> 7, colb = g & 127;
    pB[j] = (const char*)B + ((size_t)(n0 + row) * ldb) * 2 + colb;
    dB[j] = ldsc + ABYTES + (j * 4 + wave) * 1024;
  }

  auto STAGE = [&](int buf, int k0) {
    const int bo = buf * HALF;
#pragma unroll
    for (int j = 0; j < AJ; ++j) gload_lds16(pA[j] + (size_t)k0 * 2, dA[j] + bo);
#pragma unroll
    for (int j = 0; j < 4;  ++j) gload_lds16(pB[j] + (size_t)k0 * 2, dB[j] + bo);
  };

  const int wm = wave >> 1, wn = wave & 1;
  const int ra0 = wm * (BM / 2) + (lane & 15);
  const int rb0 = wn * 64 + (lane & 15);
  const int cb0 = (lane >> 4) * 16;

  floatx4 acc[MFR][4];
#pragma unroll
  for (int i = 0; i < MFR; ++i)
#pragma unroll
    for (int j = 0; j < 4; ++j) acc[i][j] = (floatx4){0.f, 0.f, 0.f, 0.f};

  STAGE(0, 0);
  int cur = 0;
  for (int k0 = 0; k0 < Keff; k0 += 64) {
    const int kn = k0 + 64;
    if (kn < Keff) {
      STAGE(cur ^ 1, kn);
      if constexpr (AJ + 4 == 6) asm volatile("s_waitcnt vmcnt(6)" ::: "memory");
      else                       asm volatile("s_waitcnt vmcnt(8)" ::: "memory");
    } else {
      asm volatile("s_waitcnt vmcnt(0)" ::: "memory");
    }
    __builtin_amdgcn_s_barrier();
    __builtin_amdgcn_sched_barrier(0);

    const int bo = cur * HALF;
    bf16x8 af[2][MFR], bfv[2][4];
#pragma unroll
    for (int kk = 0; kk < 2; ++kk) {
#pragma unroll
      for (int f = 0; f < MFR; ++f) {
        int rA = ra0 + f * 16;
        int oA = rA * 128 + kk * 64 + cb0; oA ^= ((rA & 7) << 4);
        af[kk][f] = *(const bf16x8*)(ldsc + bo + oA);
      }
#pragma unroll
      for (int f = 0; f < 4; ++f) {
        int rB = rb0 + f * 16;
        int oB = rB * 128 + kk * 64 + cb0; oB ^= ((rB & 7) << 4);
        bfv[kk][f] = *(const bf16x8*)(ldsc + bo + ABYTES + oB);
      }
    }
    __builtin_amdgcn_s_setprio(1);
#pragma unroll
    for (int kk = 0; kk < 2; ++kk)
#pragma unroll
      for (int mI = 0; mI < MFR; ++mI)
#pragma unroll
        for (int nI = 0; nI < 4; ++nI)
          acc[mI][nI] = __builtin_amdgcn_mfma_f32_16x16x32_bf16(
              af[kk][mI], bfv[kk][nI], acc[mI][nI], 0, 0, 0);
    __builtin_amdgcn_s_setprio(0);

    __builtin_amdgcn_sched_barrier(0);
    __builtin_amdgcn_s_barrier();
    cur ^= 1;
  }

  const int crow0 = mC0 + wm * (BM / 2) + ((lane >> 4) * 4);
  const int ccol0 = n0 + wn * 64 + (lane & 15);
  if constexpr (EPI == 1) {
    u16* C = (u16*)Cv;
#pragma unroll
    for (int mI = 0; mI < MFR; ++mI)
#pragma unroll
      for (int r = 0; r < 4; ++r) {
        size_t ro = (size_t)(crow0 + mI * 16 + r) * ldc + ccol0;
#pragma unroll
        for (int nI = 0; nI < 4; ++nI)
          C[ro + nI * 16] = f2bf(acc[mI][nI][r] * scale);
      }
  } else if constexpr (EPI == 2) {
    u16* C = (u16*)Cv;
#pragma unroll
    for (int mI = 0; mI < MFR; ++mI)
#pragma unroll
      for (int r = 0; r < 4; ++r) {
        const int row = crow0 + mI * 16 + r;
        size_t ro = (size_t)row * ldc + ccol0;
        float ls = 0.f;
#pragma unroll
        for (int nI = 0; nI < 4; ++nI) {
          const int col = ccol0 + nI * 16;
          float p = __expf(acc[mI][nI][r] * scale);
          if (diag && col > row) p = 0.f;
          C[ro + nI * 16] = f2bf(p);
          ls += p;
        }
        ls += __shfl_xor(ls, 1); ls += __shfl_xor(ls, 2);
        ls += __shfl_xor(ls, 4); ls += __shfl_xor(ls, 8);
        if ((lane & 15) == 0) atomicAdd(&sums[row], ls);
      }
  } else {
    float* C = (float*)Cv;
#pragma unroll
    for (int mI = 0; mI < MFR; ++mI)
#pragma unroll
      for (int r = 0; r < 4; ++r) {
        const int row = crow0 + mI * 16 + r;
        float inv = 1.0f;
        if (sums) inv = 1.0f / sums[row];      // runtime-nullable: ONE instantiation
        size_t ro = (size_t)row * ldc + ccol0;
#pragma unroll
        for (int nI = 0; nI < 4; ++nI)
          C[ro + nI * 16] = acc[mI][nI][r] * inv;
      }
  }
}

// ---------------- merged projections (round-8 proven, XCD-chunked) ----------------
__global__ __launch_bounds__(256) void proj_fused(const u16* __restrict__ xb,
                                                  const u16* __restrict__ Wt,
                                                  u16* __restrict__ qk,
                                                  u16* __restrict__ vt) {
  const int id = blockIdx.y * 16 + blockIdx.x;
  const int lin = (id & 7) * 192 + (id >> 3);        // bijective XCD chunking
  const int bx = lin & 15, by = lin >> 4;
  const u16 *A, *B; u16* C; int m0, n0, ldc;
  if (by < 64) {
    A = xb; B = Wt; C = qk;
    m0 = by * 128; n0 = bx * 128; ldc = 2048;
  } else {
    int idx = (by - 64) * 16 + bx;                   // [0,512)
    A = Wt + 2097152; B = xb; C = vt;
    m0 = (idx & 7) * 128; n0 = (idx >> 3) * 128; ldc = 8192;
  }
  gemm_core<1, 128>(A, B, C, m0, n0, 1024, 1024, ldc, 1024, 1.0f, nullptr, 0, m0);
}

// ---------------- scores: P~ = exp(q k^T / 32) bf16 + atomic row sums ----------------
// Grid 544 = exactly the causal tiles; triangular-packed, XCD-chunked (8 x 68).
__global__ __launch_bounds__(256) void gemm_scores(const u16* __restrict__ qk,
                                                   u16* __restrict__ sc16,
                                                   float* __restrict__ sums) {
  const int lin = blockIdx.x;
  const int g = (lin & 7) * 68 + (lin >> 3);         // bijective: 544 = 8*68
  const int z = g / 136, t = g - z * 136;
  int bi = (int)((sqrtf(8.f * (float)t + 1.f) - 1.f) * 0.5f);
  while ((bi + 1) * (bi + 2) / 2 <= t) ++bi;
  while (bi * (bi + 1) / 2 > t) --bi;
  const int bj = t - bi * (bi + 1) / 2;
  const u16* base = qk + (size_t)z * 4194304;
  gemm_core<2, 128>(base, base + 1024, sc16 + (size_t)z * 4194304,
                    bi * 128, bj * 128, 2048, 2048, 2048, 1024, 0.03125f,
                    sums + z * 2048, (bi == bj) ? 1 : 0, bi * 128);
}

// ---------------- PV with split-K for bi>=8 (single gemm_core instantiation) ----------------
// y in [0,24): y<8 -> c1 chunk of bi=15-y (raw -> part, rows re-based -1024);
// y in [8,16) -> c0 chunk of bi=23-y (raw -> out); y>=16 -> full bi=23-y (scaled -> out).
__global__ __launch_bounds__(256) void gemm_pv(const u16* __restrict__ sc16,
                                               const u16* __restrict__ vt,
                                               float* __restrict__ out,
                                               float* __restrict__ part,
                                               float* __restrict__ sums) {
  const int bj = blockIdx.x, z = blockIdx.z, y = blockIdx.y;
  int bi, ks, kl, mode;
  if (y < 8)       { bi = 15 - y; kl = (bi + 1) >> 1; ks = (bi + 1) - kl; mode = 2; }
  else if (y < 16) { bi = 23 - y; ks = 0; kl = (bi + 2) >> 1; mode = 1; }
  else             { bi = 23 - y; ks = 0; kl = bi + 1; mode = 0; }
  const u16* A = sc16 + (size_t)z * 4194304 + ks * 128;
  const u16* B = vt + (size_t)z * 2048 + ks * 128;
  float* outz = out + (size_t)z * 2097152;

  float* Cp; int mc; float* s;
  if (mode == 0)      { Cp = outz; mc = bi * 128;        s = sums + z * 2048; }
  else if (mode == 1) { Cp = outz; mc = bi * 128;        s = nullptr; }
  else                { Cp = part + (size_t)z * 1048576; mc = bi * 128 - 1024; s = nullptr; }

  gemm_core<3, 128>(A, B, Cp, bi * 128, bj * 128, 2048, 8192, 1024,
                    kl * 128, 1.0f, s, 0, mc);
}

// ---------------- combine: rows 1024..2047: out = (out + part) / rowsum ----------------
__global__ __launch_bounds__(256) void pv_combine(float* __restrict__ out,
                                                  const float* __restrict__ part,
                                                  const float* __restrict__ sums) {
  const int z = blockIdx.y, r = blockIdx.x;          // r in [0,1024)
  const int row = 1024 + r;
  const float inv = 1.0f / sums[z * 2048 + row];
  float4* o4 = (float4*)(out + (size_t)z * 2097152 + (size_t)row * 1024);
  const float4* p4 = (const float4*)(part + (size_t)z * 1048576 + (size_t)r * 1024);
  const int i = threadIdx.x;                         // 256 float4 = 1024 floats
  float4 a = o4[i]; float4 b = p4[i];
  a.x = (a.x + b.x) * inv; a.y = (a.y + b.y) * inv;
  a.z = (a.z + b.z) * inv; a.w = (a.w + b.w) * inv;
  o4[i] = a;
}

// ---------------- launch ----------------
extern "C" void kernel_launch(void* const* d_in, const int* in_sizes, int n_in,
                              void* d_out, int out_size, void* d_ws, size_t ws_size,
                              hipStream_t stream) {
  const float* x  = (const float*)d_in[0];
  const float* Wq = (const float*)d_in[1];
  const float* Wk = (const float*)d_in[2];
  const float* Wv = (const float*)d_in[3];
  float* out = (float*)d_out;
  char* ws = (char*)d_ws;

  const size_t MB = 1ull << 20;
  u16*  xb   = (u16*)(ws);              // 16 MiB : x bf16           [8192][1024]
  u16*  Wt   = (u16*)(ws + 16 * MB);    //  6 MiB : Wq^T|Wk^T|Wv^T   [3][1024][1024]
  u16*  qk   = (u16*)(ws + 22 * MB);    // 32 MiB : [q|k] bf16       [4*2048][2048]
  u16*  vt   = (u16*)(ws + 54 * MB);    // 16 MiB : v^T bf16         [1024][8192]
  u16*  sc16 = (u16*)(ws + 70 * MB);    // 32 MiB : P~ bf16          [4][2048][2048]
  float* part = (float*)(ws + 102 * MB); // 16 MiB : PV c1 partial   [4][1024][1024]
  float* sums = (float*)(ws + 118 * MB); // 32 KiB : row sums        [4][2048]

  hipMemsetAsync(sums, 0, NBATCH * 2048 * sizeof(float), stream);

  convert_x_kernel<<<8192, 256, 0, stream>>>((const float4*)x, xb);
  transpose_w_kernel<<<dim3(32, 32, 3), dim3(32, 8), 0, stream>>>(Wq, Wk, Wv, Wt);

  // all projections in one dispatch: 1536 blocks, XCD-chunked
  proj_fused<<<dim3(16, 96), 256, 0, stream>>>(xb, Wt, qk, vt);

  // P~ = exp(q k^T / 32) bf16 + row sums : 544 blocks exact
  gemm_scores<<<544, 256, 0, stream>>>(qk, sc16, sums);

  // out = P~ V / rowsum; split-K for bi>=8 : 768 blocks
  gemm_pv<<<dim3(8, 24, 4), 256, 0, stream>>>(sc16, vt, out, part, sums);

  // combine split rows
  pv_combine<<<dim3(1024, 4), 256, 0, stream>>>(out, part, sums);
}

// Round 11
// 151.563 us; speedup vs baseline: 1.1696x; 1.0687x over previous
//
#include <hip/hip_runtime.h>
#include <math.h>

typedef unsigned short u16;
typedef __bf16 bf16x8 __attribute__((ext_vector_type(8)));
typedef float floatx4 __attribute__((ext_vector_type(4)));

#define S_LEN 2048
#define NBATCH 4

__device__ __forceinline__ u16 f2bf(float f) {
  union { float f; unsigned u; } v; v.f = f;
  unsigned r = v.u + 0x7FFFu + ((v.u >> 16) & 1u);
  return (u16)(r >> 16);
}

__device__ __forceinline__ void gload_lds16(const void* g, void* l) {
  __builtin_amdgcn_global_load_lds(
      (__attribute__((address_space(1))) const void*)g,
      (__attribute__((address_space(3))) void*)l, 16, 0, 0);
}

// ---------------- convert x (fp32 -> bf16), vectorized ----------------
__global__ __launch_bounds__(256) void convert_x_kernel(const float4* __restrict__ x4,
                                                        u16* __restrict__ xb) {
  int i = blockIdx.x * 256 + threadIdx.x;   // n4 = 2,097,152 exactly
  float4 v = x4[i];
  ushort4 o;
  o.x = f2bf(v.x); o.y = f2bf(v.y); o.z = f2bf(v.z); o.w = f2bf(v.w);
  ((ushort4*)xb)[i] = o;
}

// ------------- transpose + convert weights: Wt[w][e][d] = bf16(W_w[d][e]) -------------
__global__ __launch_bounds__(256) void transpose_w_kernel(const float* __restrict__ Wq,
                                                          const float* __restrict__ Wk,
                                                          const float* __restrict__ Wv,
                                                          u16* __restrict__ Wt) {
  int w = blockIdx.z;
  const float* W = (w == 0) ? Wq : ((w == 1) ? Wk : Wv);
  u16* T = Wt + (size_t)w * 1048576;
  __shared__ float tile[32][33];
  int e0 = blockIdx.x * 32, d0 = blockIdx.y * 32;
  int tx = threadIdx.x, ty = threadIdx.y;   // block (32,8)
#pragma unroll
  for (int j = ty; j < 32; j += 8)
    tile[j][tx] = W[(size_t)(d0 + j) * 1024 + e0 + tx];
  __syncthreads();
#pragma unroll
  for (int j = ty; j < 32; j += 8)
    T[(size_t)(e0 + j) * 1024 + d0 + tx] = f2bf(tile[tx][j]);
}

// ---------------- core C = A * B^T (proven 2-phase 128x128, BK=64) ----------------
// EPI epilogues: 1 = bf16 store (proj);
//   2 = scores: p=exp(acc*scale) bf16, diag mask col>row -> 0, atomic row sums;
//   3 = PV fp32 store scaled by 1/sums[row] (sums nullable at runtime;
//       ONE instantiation per kernel — LDS budget!).
template <int EPI, int BM>
__device__ __forceinline__ void gemm_core(
    const u16* __restrict__ A, const u16* __restrict__ B, void* __restrict__ Cv,
    int m0, int n0, int lda, int ldb, int ldc, int Keff, float scale,
    float* __restrict__ sums, int diag, int mC0) {
  constexpr int ABYTES = BM * 128;
  constexpr int AJ = BM / 32;
  constexpr int MFR = BM / 32;
  constexpr int HALF = ABYTES + 16384;

  __shared__ u16 lds_t[2 * (BM * 64 + 128 * 64)];
  char* ldsc = (char*)lds_t;

  const int t = threadIdx.x, wave = t >> 6, lane = t & 63;

  const char* pA[AJ]; char* dA[AJ];
  const char* pB[4];  char* dB[4];
#pragma unroll
  for (int j = 0; j < AJ; ++j) {
    int o = (j * 4 + wave) * 1024 + lane * 16;
    int g = o ^ (((o >> 7) & 7) << 4);
    int row = g >> 7, colb = g & 127;
    pA[j] = (const char*)A + ((size_t)(m0 + row) * lda) * 2 + colb;
    dA[j] = ldsc + (j * 4 + wave) * 1024;
  }
#pragma unroll
  for (int j = 0; j < 4; ++j) {
    int o = (j * 4 + wave) * 1024 + lane * 16;
    int g = o ^ (((o >> 7) & 7) << 4);
    int row = g >> 7, colb = g & 127;
    pB[j] = (const char*)B + ((size_t)(n0 + row) * ldb) * 2 + colb;
    dB[j] = ldsc + ABYTES + (j * 4 + wave) * 1024;
  }

  auto STAGE = [&](int buf, int k0) {
    const int bo = buf * HALF;
#pragma unroll
    for (int j = 0; j < AJ; ++j) gload_lds16(pA[j] + (size_t)k0 * 2, dA[j] + bo);
#pragma unroll
    for (int j = 0; j < 4;  ++j) gload_lds16(pB[j] + (size_t)k0 * 2, dB[j] + bo);
  };

  const int wm = wave >> 1, wn = wave & 1;
  const int ra0 = wm * (BM / 2) + (lane & 15);
  const int rb0 = wn * 64 + (lane & 15);
  const int cb0 = (lane >> 4) * 16;

  floatx4 acc[MFR][4];
#pragma unroll
  for (int i = 0; i < MFR; ++i)
#pragma unroll
    for (int j = 0; j < 4; ++j) acc[i][j] = (floatx4){0.f, 0.f, 0.f, 0.f};

  STAGE(0, 0);
  int cur = 0;
  for (int k0 = 0; k0 < Keff; k0 += 64) {
    const int kn = k0 + 64;
    if (kn < Keff) {
      STAGE(cur ^ 1, kn);
      if constexpr (AJ + 4 == 6) asm volatile("s_waitcnt vmcnt(6)" ::: "memory");
      else                       asm volatile("s_waitcnt vmcnt(8)" ::: "memory");
    } else {
      asm volatile("s_waitcnt vmcnt(0)" ::: "memory");
    }
    __builtin_amdgcn_s_barrier();
    __builtin_amdgcn_sched_barrier(0);

    const int bo = cur * HALF;
    bf16x8 af[2][MFR], bfv[2][4];
#pragma unroll
    for (int kk = 0; kk < 2; ++kk) {
#pragma unroll
      for (int f = 0; f < MFR; ++f) {
        int rA = ra0 + f * 16;
        int oA = rA * 128 + kk * 64 + cb0; oA ^= ((rA & 7) << 4);
        af[kk][f] = *(const bf16x8*)(ldsc + bo + oA);
      }
#pragma unroll
      for (int f = 0; f < 4; ++f) {
        int rB = rb0 + f * 16;
        int oB = rB * 128 + kk * 64 + cb0; oB ^= ((rB & 7) << 4);
        bfv[kk][f] = *(const bf16x8*)(ldsc + bo + ABYTES + oB);
      }
    }
    __builtin_amdgcn_s_setprio(1);
#pragma unroll
    for (int kk = 0; kk < 2; ++kk)
#pragma unroll
      for (int mI = 0; mI < MFR; ++mI)
#pragma unroll
        for (int nI = 0; nI < 4; ++nI)
          acc[mI][nI] = __builtin_amdgcn_mfma_f32_16x16x32_bf16(
              af[kk][mI], bfv[kk][nI], acc[mI][nI], 0, 0, 0);
    __builtin_amdgcn_s_setprio(0);

    __builtin_amdgcn_sched_barrier(0);
    __builtin_amdgcn_s_barrier();
    cur ^= 1;
  }

  const int crow0 = mC0 + wm * (BM / 2) + ((lane >> 4) * 4);
  const int ccol0 = n0 + wn * 64 + (lane & 15);
  if constexpr (EPI == 1) {
    u16* C = (u16*)Cv;
#pragma unroll
    for (int mI = 0; mI < MFR; ++mI)
#pragma unroll
      for (int r = 0; r < 4; ++r) {
        size_t ro = (size_t)(crow0 + mI * 16 + r) * ldc + ccol0;
#pragma unroll
        for (int nI = 0; nI < 4; ++nI)
          C[ro + nI * 16] = f2bf(acc[mI][nI][r] * scale);
      }
  } else if constexpr (EPI == 2) {
    u16* C = (u16*)Cv;
#pragma unroll
    for (int mI = 0; mI < MFR; ++mI)
#pragma unroll
      for (int r = 0; r < 4; ++r) {
        const int row = crow0 + mI * 16 + r;
        size_t ro = (size_t)row * ldc + ccol0;
        float ls = 0.f;
#pragma unroll
        for (int nI = 0; nI < 4; ++nI) {
          const int col = ccol0 + nI * 16;
          float p = __expf(acc[mI][nI][r] * scale);
          if (diag && col > row) p = 0.f;
          C[ro + nI * 16] = f2bf(p);
          ls += p;
        }
        ls += __shfl_xor(ls, 1); ls += __shfl_xor(ls, 2);
        ls += __shfl_xor(ls, 4); ls += __shfl_xor(ls, 8);
        if ((lane & 15) == 0) atomicAdd(&sums[row], ls);
      }
  } else {
    float* C = (float*)Cv;
#pragma unroll
    for (int mI = 0; mI < MFR; ++mI)
#pragma unroll
      for (int r = 0; r < 4; ++r) {
        const int row = crow0 + mI * 16 + r;
        float inv = 1.0f;
        if (sums) inv = 1.0f / sums[row];      // runtime-nullable: ONE instantiation
        size_t ro = (size_t)row * ldc + ccol0;
#pragma unroll
        for (int nI = 0; nI < 4; ++nI)
          C[ro + nI * 16] = acc[mI][nI][r] * inv;
      }
  }
}

// ---------------- merged projections (round-8 proven, XCD-chunked) ----------------
__global__ __launch_bounds__(256) void proj_fused(const u16* __restrict__ xb,
                                                  const u16* __restrict__ Wt,
                                                  u16* __restrict__ qk,
                                                  u16* __restrict__ vt) {
  const int id = blockIdx.y * 16 + blockIdx.x;
  const int lin = (id & 7) * 192 + (id >> 3);        // bijective XCD chunking
  const int bx = lin & 15, by = lin >> 4;
  const u16 *A, *B; u16* C; int m0, n0, ldc;
  if (by < 64) {
    A = xb; B = Wt; C = qk;
    m0 = by * 128; n0 = bx * 128; ldc = 2048;
  } else {
    int idx = (by - 64) * 16 + bx;                   // [0,512)
    A = Wt + 2097152; B = xb; C = vt;
    m0 = (idx & 7) * 128; n0 = (idx >> 3) * 128; ldc = 8192;
  }
  gemm_core<1, 128>(A, B, C, m0, n0, 1024, 1024, ldc, 1024, 1.0f, nullptr, 0, m0);
}

// ---------------- scores: P~ = exp(q k^T / 32) bf16 + atomic row sums ----------------
// Grid 544 = exactly the causal tiles; triangular-packed, XCD-chunked (8 x 68).
__global__ __launch_bounds__(256) void gemm_scores(const u16* __restrict__ qk,
                                                   u16* __restrict__ sc16,
                                                   float* __restrict__ sums) {
  const int lin = blockIdx.x;
  const int g = (lin & 7) * 68 + (lin >> 3);         // bijective: 544 = 8*68
  const int z = g / 136, t = g - z * 136;
  int bi = (int)((sqrtf(8.f * (float)t + 1.f) - 1.f) * 0.5f);
  while ((bi + 1) * (bi + 2) / 2 <= t) ++bi;
  while (bi * (bi + 1) / 2 > t) --bi;
  const int bj = t - bi * (bi + 1) / 2;
  const u16* base = qk + (size_t)z * 4194304;
  gemm_core<2, 128>(base, base + 1024, sc16 + (size_t)z * 4194304,
                    bi * 128, bj * 128, 2048, 2048, 2048, 1024, 0.03125f,
                    sums + z * 2048, (bi == bj) ? 1 : 0, bi * 128);
}

// ---------------- PV monolithic (round-8-proven shape), scaled by 1/rowsum ----------------
// 512 blocks (8,16,4), big-Keff rows first; K capped per block row.
__global__ __launch_bounds__(256) void gemm_pv(const u16* __restrict__ sc16,
                                               const u16* __restrict__ vt,
                                               float* __restrict__ out,
                                               float* __restrict__ sums) {
  const int bj = blockIdx.x, z = blockIdx.z;
  const int bi = (int)gridDim.y - 1 - (int)blockIdx.y;   // big-Keff blocks first
  const int Keff = (bi + 1) * 128;
  gemm_core<3, 128>(sc16 + (size_t)z * 4194304, vt + (size_t)z * 2048,
                    out + (size_t)z * 2097152,
                    bi * 128, bj * 128, 2048, 8192, 1024, Keff, 1.0f,
                    sums + z * 2048, 0, bi * 128);
}

// ---------------- launch ----------------
extern "C" void kernel_launch(void* const* d_in, const int* in_sizes, int n_in,
                              void* d_out, int out_size, void* d_ws, size_t ws_size,
                              hipStream_t stream) {
  const float* x  = (const float*)d_in[0];
  const float* Wq = (const float*)d_in[1];
  const float* Wk = (const float*)d_in[2];
  const float* Wv = (const float*)d_in[3];
  float* out = (float*)d_out;
  char* ws = (char*)d_ws;

  const size_t MB = 1ull << 20;
  u16*  xb   = (u16*)(ws);              // 16 MiB : x bf16           [8192][1024]
  u16*  Wt   = (u16*)(ws + 16 * MB);    //  6 MiB : Wq^T|Wk^T|Wv^T   [3][1024][1024]
  u16*  qk   = (u16*)(ws + 22 * MB);    // 32 MiB : [q|k] bf16       [4*2048][2048]
  u16*  vt   = (u16*)(ws + 54 * MB);    // 16 MiB : v^T bf16         [1024][8192]
  u16*  sc16 = (u16*)(ws + 70 * MB);    // 32 MiB : P~ bf16          [4][2048][2048]
  float* sums = (float*)(ws + 102 * MB); // 32 KiB : row sums        [4][2048]

  hipMemsetAsync(sums, 0, NBATCH * 2048 * sizeof(float), stream);

  convert_x_kernel<<<8192, 256, 0, stream>>>((const float4*)x, xb);
  transpose_w_kernel<<<dim3(32, 32, 3), dim3(32, 8), 0, stream>>>(Wq, Wk, Wv, Wt);

  // all projections in one dispatch: 1536 blocks, XCD-chunked
  proj_fused<<<dim3(16, 96), 256, 0, stream>>>(xb, Wt, qk, vt);

  // P~ = exp(q k^T / 32) bf16 + row sums : 544 blocks exact
  gemm_scores<<<544, 256, 0, stream>>>(qk, sc16, sums);

  // out = P~ V / rowsum : 512 blocks, big rows first
  gemm_pv<<<dim3(8, 16, 4), 256, 0, stream>>>(sc16, vt, out, sums);
}

// Round 12
// 142.912 us; speedup vs baseline: 1.2404x; 1.0605x over previous
//
#include <hip/hip_runtime.h>
#include <math.h>

typedef unsigned short u16;
typedef __bf16 bf16x8 __attribute__((ext_vector_type(8)));
typedef float floatx4 __attribute__((ext_vector_type(4)));

#define S_LEN 2048
#define NBATCH 4

__device__ __forceinline__ u16 f2bf(float f) {
  union { float f; unsigned u; } v; v.f = f;
  unsigned r = v.u + 0x7FFFu + ((v.u >> 16) & 1u);
  return (u16)(r >> 16);
}

__device__ __forceinline__ void gload_lds16(const void* g, void* l) {
  __builtin_amdgcn_global_load_lds(
      (__attribute__((address_space(1))) const void*)g,
      (__attribute__((address_space(3))) void*)l, 16, 0, 0);
}

// -------- fused prep: x fp32->bf16 (blocks 0..8191) + W transpose (blocks 8192..11263) --------
__global__ __launch_bounds__(256) void prep_kernel(const float4* __restrict__ x4,
                                                   u16* __restrict__ xb,
                                                   const float* __restrict__ Wq,
                                                   const float* __restrict__ Wk,
                                                   const float* __restrict__ Wv,
                                                   u16* __restrict__ Wt) {
  const int b = blockIdx.x, t = threadIdx.x;
  if (b < 8192) {
    int i = b * 256 + t;                     // n4 = 2,097,152 exactly
    float4 v = x4[i];
    ushort4 o;
    o.x = f2bf(v.x); o.y = f2bf(v.y); o.z = f2bf(v.z); o.w = f2bf(v.w);
    ((ushort4*)xb)[i] = o;
  } else {
    const int idx = b - 8192;                // [0, 3072)
    const int w = idx >> 10, r2 = idx & 1023;
    const float* W = (w == 0) ? Wq : ((w == 1) ? Wk : Wv);
    u16* T = Wt + (size_t)w * 1048576;
    __shared__ float tile[32][33];
    const int e0 = (r2 & 31) * 32, d0 = (r2 >> 5) * 32;
    const int tx = t & 31, ty = t >> 5;      // (32,8)
#pragma unroll
    for (int j = ty; j < 32; j += 8)
      tile[j][tx] = W[(size_t)(d0 + j) * 1024 + e0 + tx];
    __syncthreads();
#pragma unroll
    for (int j = ty; j < 32; j += 8)
      T[(size_t)(e0 + j) * 1024 + d0 + tx] = f2bf(tile[tx][j]);
  }
}

// ---------------- core C = A * B^T (proven 2-phase 128x128, BK=64) ----------------
// WAVES=4 reduces exactly to the round-5..11-proven code. WAVES=8: same tile &
// schedule, per-wave output 32x64 (acc[2][4]), staging slot = j*WAVES+wave,
// 4 loads/thread -> vmcnt(4).
// EPI: 1 = bf16 store; 2 = scores exp+mask+atomic row sums; 3 = fp32 / sums[row].
template <int EPI, int BM, int WAVES>
__device__ __forceinline__ void gemm_core(
    const u16* __restrict__ A, const u16* __restrict__ B, void* __restrict__ Cv,
    int m0, int n0, int lda, int ldb, int ldc, int Keff, float scale,
    float* __restrict__ sums, int diag, int mC0) {
  constexpr int ABYTES = BM * 128;                 // A-tile bytes (BM x 64 bf16)
  constexpr int ASLOTS = (BM * 128 / 1024) / WAVES; // 1KB staging slots per wave (A)
  constexpr int BSLOTS = 16 / WAVES;                // B tile = 16KB
  constexpr int WROWS = BM / (WAVES / 2);           // rows per wave
  constexpr int MFR = WROWS / 16;                   // 16-row fragments per wave
  constexpr int HALF = ABYTES + 16384;

  __shared__ u16 lds_t[2 * (BM * 64 + 128 * 64)];
  char* ldsc = (char*)lds_t;

  const int t = threadIdx.x, wave = t >> 6, lane = t & 63;

  const char* pA[ASLOTS]; char* dA[ASLOTS];
  const char* pB[BSLOTS]; char* dB[BSLOTS];
#pragma unroll
  for (int j = 0; j < ASLOTS; ++j) {
    int o = (j * WAVES + wave) * 1024 + lane * 16;  // linear LDS byte this lane fills
    int g = o ^ (((o >> 7) & 7) << 4);              // inverse-swizzled tile byte
    int row = g >> 7, colb = g & 127;
    pA[j] = (const char*)A + ((size_t)(m0 + row) * lda) * 2 + colb;
    dA[j] = ldsc + (j * WAVES + wave) * 1024;       // wave-uniform base
  }
#pragma unroll
  for (int j = 0; j < BSLOTS; ++j) {
    int o = (j * WAVES + wave) * 1024 + lane * 16;
    int g = o ^ (((o >> 7) & 7) << 4);
    int row = g >> 7, colb = g & 127;
    pB[j] = (const char*)B + ((size_t)(n0 + row) * ldb) * 2 + colb;
    dB[j] = ldsc + ABYTES + (j * WAVES + wave) * 1024;
  }

  auto STAGE = [&](int buf, int k0) {
    const int bo = buf * HALF;
#pragma unroll
    for (int j = 0; j < ASLOTS; ++j) gload_lds16(pA[j] + (size_t)k0 * 2, dA[j] + bo);
#pragma unroll
    for (int j = 0; j < BSLOTS; ++j) gload_lds16(pB[j] + (size_t)k0 * 2, dB[j] + bo);
  };

  const int wm = wave >> 1, wn = wave & 1;
  const int ra0 = wm * WROWS + (lane & 15);
  const int rb0 = wn * 64 + (lane & 15);
  const int cb0 = (lane >> 4) * 16;

  floatx4 acc[MFR][4];
#pragma unroll
  for (int i = 0; i < MFR; ++i)
#pragma unroll
    for (int j = 0; j < 4; ++j) acc[i][j] = (floatx4){0.f, 0.f, 0.f, 0.f};

  STAGE(0, 0);
  int cur = 0;
  for (int k0 = 0; k0 < Keff; k0 += 64) {
    const int kn = k0 + 64;
    if (kn < Keff) {
      STAGE(cur ^ 1, kn);
      // wait for previous tile's loads only (issued ASLOTS+BSLOTS before)
      if constexpr (ASLOTS + BSLOTS == 4) asm volatile("s_waitcnt vmcnt(4)" ::: "memory");
      else if constexpr (ASLOTS + BSLOTS == 6) asm volatile("s_waitcnt vmcnt(6)" ::: "memory");
      else                                asm volatile("s_waitcnt vmcnt(8)" ::: "memory");
    } else {
      asm volatile("s_waitcnt vmcnt(0)" ::: "memory");
    }
    __builtin_amdgcn_s_barrier();
    __builtin_amdgcn_sched_barrier(0);

    const int bo = cur * HALF;
    bf16x8 af[2][MFR], bfv[2][4];
#pragma unroll
    for (int kk = 0; kk < 2; ++kk) {
#pragma unroll
      for (int f = 0; f < MFR; ++f) {
        int rA = ra0 + f * 16;
        int oA = rA * 128 + kk * 64 + cb0; oA ^= ((rA & 7) << 4);
        af[kk][f] = *(const bf16x8*)(ldsc + bo + oA);
      }
#pragma unroll
      for (int f = 0; f < 4; ++f) {
        int rB = rb0 + f * 16;
        int oB = rB * 128 + kk * 64 + cb0; oB ^= ((rB & 7) << 4);
        bfv[kk][f] = *(const bf16x8*)(ldsc + bo + ABYTES + oB);
      }
    }
    __builtin_amdgcn_s_setprio(1);
#pragma unroll
    for (int kk = 0; kk < 2; ++kk)
#pragma unroll
      for (int mI = 0; mI < MFR; ++mI)
#pragma unroll
        for (int nI = 0; nI < 4; ++nI)
          acc[mI][nI] = __builtin_amdgcn_mfma_f32_16x16x32_bf16(
              af[kk][mI], bfv[kk][nI], acc[mI][nI], 0, 0, 0);
    __builtin_amdgcn_s_setprio(0);

    __builtin_amdgcn_sched_barrier(0);
    __builtin_amdgcn_s_barrier();
    cur ^= 1;
  }

  const int crow0 = mC0 + wm * WROWS + ((lane >> 4) * 4);
  const int ccol0 = n0 + wn * 64 + (lane & 15);
  if constexpr (EPI == 1) {
    u16* C = (u16*)Cv;
#pragma unroll
    for (int mI = 0; mI < MFR; ++mI)
#pragma unroll
      for (int r = 0; r < 4; ++r) {
        size_t ro = (size_t)(crow0 + mI * 16 + r) * ldc + ccol0;
#pragma unroll
        for (int nI = 0; nI < 4; ++nI)
          C[ro + nI * 16] = f2bf(acc[mI][nI][r] * scale);
      }
  } else if constexpr (EPI == 2) {
    u16* C = (u16*)Cv;
#pragma unroll
    for (int mI = 0; mI < MFR; ++mI)
#pragma unroll
      for (int r = 0; r < 4; ++r) {
        const int row = crow0 + mI * 16 + r;
        size_t ro = (size_t)row * ldc + ccol0;
        float ls = 0.f;
#pragma unroll
        for (int nI = 0; nI < 4; ++nI) {
          const int col = ccol0 + nI * 16;
          float p = __expf(acc[mI][nI][r] * scale);
          if (diag && col > row) p = 0.f;
          C[ro + nI * 16] = f2bf(p);
          ls += p;
        }
        ls += __shfl_xor(ls, 1); ls += __shfl_xor(ls, 2);
        ls += __shfl_xor(ls, 4); ls += __shfl_xor(ls, 8);
        if ((lane & 15) == 0) atomicAdd(&sums[row], ls);
      }
  } else {
    float* C = (float*)Cv;
#pragma unroll
    for (int mI = 0; mI < MFR; ++mI)
#pragma unroll
      for (int r = 0; r < 4; ++r) {
        const int row = crow0 + mI * 16 + r;
        float inv = 1.0f;
        if (sums) inv = 1.0f / sums[row];
        size_t ro = (size_t)row * ldc + ccol0;
#pragma unroll
        for (int nI = 0; nI < 4; ++nI)
          C[ro + nI * 16] = acc[mI][nI][r] * inv;
      }
  }
}

// ---------------- merged projections (round-8..11 proven, XCD-chunked, 4-wave) ----------------
__global__ __launch_bounds__(256) void proj_fused(const u16* __restrict__ xb,
                                                  const u16* __restrict__ Wt,
                                                  u16* __restrict__ qk,
                                                  u16* __restrict__ vt) {
  const int id = blockIdx.y * 16 + blockIdx.x;
  const int lin = (id & 7) * 192 + (id >> 3);        // bijective XCD chunking
  const int bx = lin & 15, by = lin >> 4;
  const u16 *A, *B; u16* C; int m0, n0, ldc;
  if (by < 64) {
    A = xb; B = Wt; C = qk;
    m0 = by * 128; n0 = bx * 128; ldc = 2048;
  } else {
    int idx = (by - 64) * 16 + bx;                   // [0,512)
    A = Wt + 2097152; B = xb; C = vt;
    m0 = (idx & 7) * 128; n0 = (idx >> 3) * 128; ldc = 8192;
  }
  gemm_core<1, 128, 4>(A, B, C, m0, n0, 1024, 1024, ldc, 1024, 1.0f, nullptr, 0, m0);
}

// ---------------- scores: P~ = exp(q k^T / 32) bf16 + atomic row sums (8-wave) ----------------
// Grid 544 = exactly the causal tiles; triangular-packed, XCD-chunked (8 x 68).
__global__ __launch_bounds__(512) void gemm_scores(const u16* __restrict__ qk,
                                                   u16* __restrict__ sc16,
                                                   float* __restrict__ sums) {
  const int lin = blockIdx.x;
  const int g = (lin & 7) * 68 + (lin >> 3);         // bijective: 544 = 8*68
  const int z = g / 136, t = g - z * 136;
  int bi = (int)((sqrtf(8.f * (float)t + 1.f) - 1.f) * 0.5f);
  while ((bi + 1) * (bi + 2) / 2 <= t) ++bi;
  while (bi * (bi + 1) / 2 > t) --bi;
  const int bj = t - bi * (bi + 1) / 2;
  const u16* base = qk + (size_t)z * 4194304;
  gemm_core<2, 128, 8>(base, base + 1024, sc16 + (size_t)z * 4194304,
                       bi * 128, bj * 128, 2048, 2048, 2048, 1024, 0.03125f,
                       sums + z * 2048, (bi == bj) ? 1 : 0, bi * 128);
}

// ---------------- PV monolithic (8-wave), scaled by 1/rowsum ----------------
// 512 blocks (8,16,4), big-Keff rows first; K capped per block row.
__global__ __launch_bounds__(512) void gemm_pv(const u16* __restrict__ sc16,
                                               const u16* __restrict__ vt,
                                               float* __restrict__ out,
                                               float* __restrict__ sums) {
  const int bj = blockIdx.x, z = blockIdx.z;
  const int bi = (int)gridDim.y - 1 - (int)blockIdx.y;   // big-Keff blocks first
  const int Keff = (bi + 1) * 128;
  gemm_core<3, 128, 8>(sc16 + (size_t)z * 4194304, vt + (size_t)z * 2048,
                       out + (size_t)z * 2097152,
                       bi * 128, bj * 128, 2048, 8192, 1024, Keff, 1.0f,
                       sums + z * 2048, 0, bi * 128);
}

// ---------------- launch ----------------
extern "C" void kernel_launch(void* const* d_in, const int* in_sizes, int n_in,
                              void* d_out, int out_size, void* d_ws, size_t ws_size,
                              hipStream_t stream) {
  const float* x  = (const float*)d_in[0];
  const float* Wq = (const float*)d_in[1];
  const float* Wk = (const float*)d_in[2];
  const float* Wv = (const float*)d_in[3];
  float* out = (float*)d_out;
  char* ws = (char*)d_ws;

  const size_t MB = 1ull << 20;
  u16*  xb   = (u16*)(ws);              // 16 MiB : x bf16           [8192][1024]
  u16*  Wt   = (u16*)(ws + 16 * MB);    //  6 MiB : Wq^T|Wk^T|Wv^T   [3][1024][1024]
  u16*  qk   = (u16*)(ws + 22 * MB);    // 32 MiB : [q|k] bf16       [4*2048][2048]
  u16*  vt   = (u16*)(ws + 54 * MB);    // 16 MiB : v^T bf16         [1024][8192]
  u16*  sc16 = (u16*)(ws + 70 * MB);    // 32 MiB : P~ bf16          [4][2048][2048]
  float* sums = (float*)(ws + 102 * MB); // 32 KiB : row sums        [4][2048]

  hipMemsetAsync(sums, 0, NBATCH * 2048 * sizeof(float), stream);

  // x->bf16 + W transpose in one dispatch
  prep_kernel<<<11264, 256, 0, stream>>>((const float4*)x, xb, Wq, Wk, Wv, Wt);

  // all projections in one dispatch: 1536 blocks, XCD-chunked (4-wave, frozen)
  proj_fused<<<dim3(16, 96), 256, 0, stream>>>(xb, Wt, qk, vt);

  // P~ = exp(q k^T / 32) bf16 + row sums : 544 blocks x 512 threads
  gemm_scores<<<544, 512, 0, stream>>>(qk, sc16, sums);

  // out = P~ V / rowsum : 512 blocks x 512 threads, big rows first
  gemm_pv<<<dim3(8, 16, 4), 512, 0, stream>>>(sc16, vt, out, sums);
}

// Round 13
// 134.020 us; speedup vs baseline: 1.3227x; 1.0663x over previous
//
#include <hip/hip_runtime.h>
#include <math.h>

typedef unsigned short u16;
typedef __bf16 bf16x8 __attribute__((ext_vector_type(8)));
typedef float floatx4 __attribute__((ext_vector_type(4)));

#define S_LEN 2048
#define NBATCH 4

__device__ __forceinline__ u16 f2bf(float f) {
  union { float f; unsigned u; } v; v.f = f;
  unsigned r = v.u + 0x7FFFu + ((v.u >> 16) & 1u);
  return (u16)(r >> 16);
}

__device__ __forceinline__ void gload_lds16(const void* g, void* l) {
  __builtin_amdgcn_global_load_lds(
      (__attribute__((address_space(1))) const void*)g,
      (__attribute__((address_space(3))) void*)l, 16, 0, 0);
}

// -------- fused prep: x fp32->bf16 (0..8191) + W transpose (8192..11263) + sums=0 --------
__global__ __launch_bounds__(256) void prep_kernel(const float4* __restrict__ x4,
                                                   u16* __restrict__ xb,
                                                   const float* __restrict__ Wq,
                                                   const float* __restrict__ Wk,
                                                   const float* __restrict__ Wv,
                                                   u16* __restrict__ Wt,
                                                   float* __restrict__ sums) {
  const int b = blockIdx.x, t = threadIdx.x;
  if (b < 8192) {
    int i = b * 256 + t;                     // n4 = 2,097,152 exactly
    float4 v = x4[i];
    ushort4 o;
    o.x = f2bf(v.x); o.y = f2bf(v.y); o.z = f2bf(v.z); o.w = f2bf(v.w);
    ((ushort4*)xb)[i] = o;
  } else if (b < 11264) {
    const int idx = b - 8192;                // [0, 3072)
    const int w = idx >> 10, r2 = idx & 1023;
    const float* W = (w == 0) ? Wq : ((w == 1) ? Wk : Wv);
    u16* T = Wt + (size_t)w * 1048576;
    __shared__ float tile[32][33];
    const int e0 = (r2 & 31) * 32, d0 = (r2 >> 5) * 32;
    const int tx = t & 31, ty = t >> 5;      // (32,8)
#pragma unroll
    for (int j = ty; j < 32; j += 8)
      tile[j][tx] = W[(size_t)(d0 + j) * 1024 + e0 + tx];
    __syncthreads();
#pragma unroll
    for (int j = ty; j < 32; j += 8)
      T[(size_t)(e0 + j) * 1024 + d0 + tx] = f2bf(tile[tx][j]);
  } else {
    sums[(b - 11264) * 256 + t] = 0.0f;      // 32 blocks x 256 = 8192 floats
  }
}

// ---------------- core C = A * B^T (proven 2-phase 128x128, BK=64) ----------------
// WAVES=4 / WAVES=8 as proven in rounds 5..12. NEW: runtime npass tile loop
// (single instantiation, single __shared__) so one block can process two tiles
// sequentially — used by PV for perfect (bi, 15-bi) pairing.
// EPI: 1 = bf16 store; 2 = scores exp+mask+atomic row sums; 3 = fp32 / sums[row].
template <int EPI, int BM, int WAVES>
__device__ __forceinline__ void gemm_core(
    const u16* __restrict__ A, const u16* __restrict__ B, void* __restrict__ Cv,
    int n0, int lda, int ldb, int ldc, float scale,
    float* __restrict__ sums, int diag, int npass,
    int m0_0, int Keff_0, int m0_1, int Keff_1) {
  constexpr int ABYTES = BM * 128;                 // A-tile bytes (BM x 64 bf16)
  constexpr int ASLOTS = (BM * 128 / 1024) / WAVES; // 1KB staging slots per wave (A)
  constexpr int BSLOTS = 16 / WAVES;                // B tile = 16KB
  constexpr int WROWS = BM / (WAVES / 2);           // rows per wave
  constexpr int MFR = WROWS / 16;                   // 16-row fragments per wave
  constexpr int HALF = ABYTES + 16384;

  __shared__ u16 lds_t[2 * (BM * 64 + 128 * 64)];
  char* ldsc = (char*)lds_t;

  const int t = threadIdx.x, wave = t >> 6, lane = t & 63;
  const int wm = wave >> 1, wn = wave & 1;
  const int ra0 = wm * WROWS + (lane & 15);
  const int rb0 = wn * 64 + (lane & 15);
  const int cb0 = (lane >> 4) * 16;

  for (int p = 0; p < npass; ++p) {
    const int m0 = p ? m0_1 : m0_0;
    const int Keff = p ? Keff_1 : Keff_0;

    const char* pA[ASLOTS]; char* dA[ASLOTS];
    const char* pB[BSLOTS]; char* dB[BSLOTS];
#pragma unroll
    for (int j = 0; j < ASLOTS; ++j) {
      int o = (j * WAVES + wave) * 1024 + lane * 16;  // linear LDS byte this lane fills
      int g = o ^ (((o >> 7) & 7) << 4);              // inverse-swizzled tile byte
      int row = g >> 7, colb = g & 127;
      pA[j] = (const char*)A + ((size_t)(m0 + row) * lda) * 2 + colb;
      dA[j] = ldsc + (j * WAVES + wave) * 1024;       // wave-uniform base
    }
#pragma unroll
    for (int j = 0; j < BSLOTS; ++j) {
      int o = (j * WAVES + wave) * 1024 + lane * 16;
      int g = o ^ (((o >> 7) & 7) << 4);
      int row = g >> 7, colb = g & 127;
      pB[j] = (const char*)B + ((size_t)(n0 + row) * ldb) * 2 + colb;
      dB[j] = ldsc + ABYTES + (j * WAVES + wave) * 1024;
    }

    auto STAGE = [&](int buf, int k0) {
      const int bo = buf * HALF;
#pragma unroll
      for (int j = 0; j < ASLOTS; ++j) gload_lds16(pA[j] + (size_t)k0 * 2, dA[j] + bo);
#pragma unroll
      for (int j = 0; j < BSLOTS; ++j) gload_lds16(pB[j] + (size_t)k0 * 2, dB[j] + bo);
    };

    floatx4 acc[MFR][4];
#pragma unroll
    for (int i = 0; i < MFR; ++i)
#pragma unroll
      for (int j = 0; j < 4; ++j) acc[i][j] = (floatx4){0.f, 0.f, 0.f, 0.f};

    STAGE(0, 0);
    int cur = 0;
    for (int k0 = 0; k0 < Keff; k0 += 64) {
      const int kn = k0 + 64;
      if (kn < Keff) {
        STAGE(cur ^ 1, kn);
        if constexpr (ASLOTS + BSLOTS == 4) asm volatile("s_waitcnt vmcnt(4)" ::: "memory");
        else if constexpr (ASLOTS + BSLOTS == 6) asm volatile("s_waitcnt vmcnt(6)" ::: "memory");
        else                                asm volatile("s_waitcnt vmcnt(8)" ::: "memory");
      } else {
        asm volatile("s_waitcnt vmcnt(0)" ::: "memory");
      }
      __builtin_amdgcn_s_barrier();
      __builtin_amdgcn_sched_barrier(0);

      const int bo = cur * HALF;
      bf16x8 af[2][MFR], bfv[2][4];
#pragma unroll
      for (int kk = 0; kk < 2; ++kk) {
#pragma unroll
        for (int f = 0; f < MFR; ++f) {
          int rA = ra0 + f * 16;
          int oA = rA * 128 + kk * 64 + cb0; oA ^= ((rA & 7) << 4);
          af[kk][f] = *(const bf16x8*)(ldsc + bo + oA);
        }
#pragma unroll
        for (int f = 0; f < 4; ++f) {
          int rB = rb0 + f * 16;
          int oB = rB * 128 + kk * 64 + cb0; oB ^= ((rB & 7) << 4);
          bfv[kk][f] = *(const bf16x8*)(ldsc + bo + ABYTES + oB);
        }
      }
      __builtin_amdgcn_s_setprio(1);
#pragma unroll
      for (int kk = 0; kk < 2; ++kk)
#pragma unroll
        for (int mI = 0; mI < MFR; ++mI)
#pragma unroll
          for (int nI = 0; nI < 4; ++nI)
            acc[mI][nI] = __builtin_amdgcn_mfma_f32_16x16x32_bf16(
                af[kk][mI], bfv[kk][nI], acc[mI][nI], 0, 0, 0);
      __builtin_amdgcn_s_setprio(0);

      __builtin_amdgcn_sched_barrier(0);
      __builtin_amdgcn_s_barrier();
      cur ^= 1;
    }

    const int crow0 = m0 + wm * WROWS + ((lane >> 4) * 4);
    const int ccol0 = n0 + wn * 64 + (lane & 15);
    if constexpr (EPI == 1) {
      u16* C = (u16*)Cv;
#pragma unroll
      for (int mI = 0; mI < MFR; ++mI)
#pragma unroll
        for (int r = 0; r < 4; ++r) {
          size_t ro = (size_t)(crow0 + mI * 16 + r) * ldc + ccol0;
#pragma unroll
          for (int nI = 0; nI < 4; ++nI)
            C[ro + nI * 16] = f2bf(acc[mI][nI][r] * scale);
        }
    } else if constexpr (EPI == 2) {
      u16* C = (u16*)Cv;
#pragma unroll
      for (int mI = 0; mI < MFR; ++mI)
#pragma unroll
        for (int r = 0; r < 4; ++r) {
          const int row = crow0 + mI * 16 + r;
          size_t ro = (size_t)row * ldc + ccol0;
          float ls = 0.f;
#pragma unroll
          for (int nI = 0; nI < 4; ++nI) {
            const int col = ccol0 + nI * 16;
            float pp = __expf(acc[mI][nI][r] * scale);
            if (diag && col > row) pp = 0.f;
            C[ro + nI * 16] = f2bf(pp);
            ls += pp;
          }
          ls += __shfl_xor(ls, 1); ls += __shfl_xor(ls, 2);
          ls += __shfl_xor(ls, 4); ls += __shfl_xor(ls, 8);
          if ((lane & 15) == 0) atomicAdd(&sums[row], ls);
        }
    } else {
      float* C = (float*)Cv;
#pragma unroll
      for (int mI = 0; mI < MFR; ++mI)
#pragma unroll
        for (int r = 0; r < 4; ++r) {
          const int row = crow0 + mI * 16 + r;
          float inv = 1.0f;
          if (sums) inv = 1.0f / sums[row];
          size_t ro = (size_t)row * ldc + ccol0;
#pragma unroll
          for (int nI = 0; nI < 4; ++nI)
            C[ro + nI * 16] = acc[mI][nI][r] * inv;
        }
    }
  }
}

// ---------------- merged projections (round-8..12 proven, XCD-chunked, 4-wave) ----------------
__global__ __launch_bounds__(256) void proj_fused(const u16* __restrict__ xb,
                                                  const u16* __restrict__ Wt,
                                                  u16* __restrict__ qk,
                                                  u16* __restrict__ vt) {
  const int id = blockIdx.y * 16 + blockIdx.x;
  const int lin = (id & 7) * 192 + (id >> 3);        // bijective XCD chunking
  const int bx = lin & 15, by = lin >> 4;
  const u16 *A, *B; u16* C; int m0, n0, ldc;
  if (by < 64) {
    A = xb; B = Wt; C = qk;
    m0 = by * 128; n0 = bx * 128; ldc = 2048;
  } else {
    int idx = (by - 64) * 16 + bx;                   // [0,512)
    A = Wt + 2097152; B = xb; C = vt;
    m0 = (idx & 7) * 128; n0 = (idx >> 3) * 128; ldc = 8192;
  }
  gemm_core<1, 128, 4>(A, B, C, n0, 1024, 1024, ldc, 1.0f, nullptr, 0,
                       1, m0, 1024, 0, 0);
}

// ---------------- scores: P~ = exp(q k^T / 32) bf16 + atomic row sums (8-wave) ----------------
// Grid 544 = exactly the causal tiles; triangular-packed, XCD-chunked (8 x 68).
__global__ __launch_bounds__(512) void gemm_scores(const u16* __restrict__ qk,
                                                   u16* __restrict__ sc16,
                                                   float* __restrict__ sums) {
  const int lin = blockIdx.x;
  const int g = (lin & 7) * 68 + (lin >> 3);         // bijective: 544 = 8*68
  const int z = g / 136, t = g - z * 136;
  int bi = (int)((sqrtf(8.f * (float)t + 1.f) - 1.f) * 0.5f);
  while ((bi + 1) * (bi + 2) / 2 <= t) ++bi;
  while (bi * (bi + 1) / 2 > t) --bi;
  const int bj = t - bi * (bi + 1) / 2;
  const u16* base = qk + (size_t)z * 4194304;
  gemm_core<2, 128, 8>(base, base + 1024, sc16 + (size_t)z * 4194304,
                       bj * 128, 2048, 2048, 2048, 0.03125f,
                       sums + z * 2048, (bi == bj) ? 1 : 0,
                       1, bi * 128, 1024, 0, 0);
}

// ---------------- PV paired (8-wave): block does tiles bi=15-y THEN bi=y ----------------
// Every block processes exactly 17 K-units -> perfectly balanced. 256 blocks.
__global__ __launch_bounds__(512) void gemm_pv(const u16* __restrict__ sc16,
                                               const u16* __restrict__ vt,
                                               float* __restrict__ out,
                                               float* __restrict__ sums) {
  const int bj = blockIdx.x, z = blockIdx.z, y = blockIdx.y;   // y in [0,8)
  const int bi1 = 15 - y, bi2 = y;                             // big first
  gemm_core<3, 128, 8>(sc16 + (size_t)z * 4194304, vt + (size_t)z * 2048,
                       out + (size_t)z * 2097152,
                       bj * 128, 2048, 8192, 1024, 1.0f,
                       sums + z * 2048, 0,
                       2, bi1 * 128, (bi1 + 1) * 128, bi2 * 128, (bi2 + 1) * 128);
}

// ---------------- launch ----------------
extern "C" void kernel_launch(void* const* d_in, const int* in_sizes, int n_in,
                              void* d_out, int out_size, void* d_ws, size_t ws_size,
                              hipStream_t stream) {
  const float* x  = (const float*)d_in[0];
  const float* Wq = (const float*)d_in[1];
  const float* Wk = (const float*)d_in[2];
  const float* Wv = (const float*)d_in[3];
  float* out = (float*)d_out;
  char* ws = (char*)d_ws;

  const size_t MB = 1ull << 20;
  u16*  xb   = (u16*)(ws);              // 16 MiB : x bf16           [8192][1024]
  u16*  Wt   = (u16*)(ws + 16 * MB);    //  6 MiB : Wq^T|Wk^T|Wv^T   [3][1024][1024]
  u16*  qk   = (u16*)(ws + 22 * MB);    // 32 MiB : [q|k] bf16       [4*2048][2048]
  u16*  vt   = (u16*)(ws + 54 * MB);    // 16 MiB : v^T bf16         [1024][8192]
  u16*  sc16 = (u16*)(ws + 70 * MB);    // 32 MiB : P~ bf16          [4][2048][2048]
  float* sums = (float*)(ws + 102 * MB); // 32 KiB : row sums        [4][2048]

  // x->bf16 + W transpose + sums=0 in one dispatch
  prep_kernel<<<11296, 256, 0, stream>>>((const float4*)x, xb, Wq, Wk, Wv, Wt, sums);

  // all projections in one dispatch: 1536 blocks, XCD-chunked (4-wave, frozen)
  proj_fused<<<dim3(16, 96), 256, 0, stream>>>(xb, Wt, qk, vt);

  // P~ = exp(q k^T / 32) bf16 + row sums : 544 blocks x 512 threads
  gemm_scores<<<544, 512, 0, stream>>>(qk, sc16, sums);

  // out = P~ V / rowsum : 256 blocks x 512 threads, perfectly paired
  gemm_pv<<<dim3(8, 8, 4), 512, 0, stream>>>(sc16, vt, out, sums);
}

// Round 14
// 128.574 us; speedup vs baseline: 1.3787x; 1.0424x over previous
//
#include <hip/hip_runtime.h>
#include <math.h>

typedef unsigned short u16;
typedef __bf16 bf16x8 __attribute__((ext_vector_type(8)));
typedef float floatx4 __attribute__((ext_vector_type(4)));

#define S_LEN 2048
#define NBATCH 4

__device__ __forceinline__ u16 f2bf(float f) {
  union { float f; unsigned u; } v; v.f = f;
  unsigned r = v.u + 0x7FFFu + ((v.u >> 16) & 1u);
  return (u16)(r >> 16);
}

__device__ __forceinline__ void gload_lds16(const void* g, void* l) {
  __builtin_amdgcn_global_load_lds(
      (__attribute__((address_space(1))) const void*)g,
      (__attribute__((address_space(3))) void*)l, 16, 0, 0);
}

// -------- fused prep: xb (0..8191) | Wq,Wk straight bf16 cast (8192..10239) |
//          Wv transpose cast (10240..11263) | sums = 0 (11264..11295) --------
__global__ __launch_bounds__(256) void prep_kernel(const float4* __restrict__ x4,
                                                   u16* __restrict__ xb,
                                                   const float* __restrict__ Wq,
                                                   const float* __restrict__ Wk,
                                                   const float* __restrict__ Wv,
                                                   u16* __restrict__ Wqb,
                                                   u16* __restrict__ Wkb,
                                                   u16* __restrict__ Wvt,
                                                   float* __restrict__ sums) {
  const int b = blockIdx.x, t = threadIdx.x;
  if (b < 8192) {
    int i = b * 256 + t;                     // n4 = 2,097,152 exactly
    float4 v = x4[i];
    ushort4 o;
    o.x = f2bf(v.x); o.y = f2bf(v.y); o.z = f2bf(v.z); o.w = f2bf(v.w);
    ((ushort4*)xb)[i] = o;
  } else if (b < 10240) {
    const int idx = b - 8192;                // [0, 2048): 1024 for Wq, 1024 for Wk
    const float4* W4 = (const float4*)((idx < 1024) ? Wq : Wk);
    u16* T = (idx < 1024) ? Wqb : Wkb;
    int i = (idx & 1023) * 256 + t;          // 262144 float4 per W
    float4 v = W4[i];
    ushort4 o;
    o.x = f2bf(v.x); o.y = f2bf(v.y); o.z = f2bf(v.z); o.w = f2bf(v.w);
    ((ushort4*)T)[i] = o;
  } else if (b < 11264) {
    const int r2 = b - 10240;                // [0, 1024): 32x32 tiles of Wv^T
    __shared__ float tile[32][33];
    const int e0 = (r2 & 31) * 32, d0 = (r2 >> 5) * 32;
    const int tx = t & 31, ty = t >> 5;      // (32,8)
#pragma unroll
    for (int j = ty; j < 32; j += 8)
      tile[j][tx] = Wv[(size_t)(d0 + j) * 1024 + e0 + tx];
    __syncthreads();
#pragma unroll
    for (int j = ty; j < 32; j += 8)
      Wvt[(size_t)(e0 + j) * 1024 + d0 + tx] = f2bf(tile[tx][j]);
  } else {
    sums[(b - 11264) * 256 + t] = 0.0f;      // 32 blocks x 256 = 8192 floats
  }
}

// ---------------- core C = A * B^T (proven 2-phase 128x128, BK=64) ----------------
// WAVES=4 / WAVES=8 proven rounds 5..13; npass loop proven round 13.
// EPI: 1 = bf16 store; 2 = scores exp+mask+atomic row sums; 3 = fp32 / sums[row].
template <int EPI, int BM, int WAVES>
__device__ __forceinline__ void gemm_core(
    const u16* __restrict__ A, const u16* __restrict__ B, void* __restrict__ Cv,
    int n0, int lda, int ldb, int ldc, float scale,
    float* __restrict__ sums, int diag, int npass,
    int m0_0, int Keff_0, int m0_1, int Keff_1) {
  constexpr int ABYTES = BM * 128;
  constexpr int ASLOTS = (BM * 128 / 1024) / WAVES;
  constexpr int BSLOTS = 16 / WAVES;
  constexpr int WROWS = BM / (WAVES / 2);
  constexpr int MFR = WROWS / 16;
  constexpr int HALF = ABYTES + 16384;

  __shared__ u16 lds_t[2 * (BM * 64 + 128 * 64)];
  char* ldsc = (char*)lds_t;

  const int t = threadIdx.x, wave = t >> 6, lane = t & 63;
  const int wm = wave >> 1, wn = wave & 1;
  const int ra0 = wm * WROWS + (lane & 15);
  const int rb0 = wn * 64 + (lane & 15);
  const int cb0 = (lane >> 4) * 16;

  for (int p = 0; p < npass; ++p) {
    const int m0 = p ? m0_1 : m0_0;
    const int Keff = p ? Keff_1 : Keff_0;

    const char* pA[ASLOTS]; char* dA[ASLOTS];
    const char* pB[BSLOTS]; char* dB[BSLOTS];
#pragma unroll
    for (int j = 0; j < ASLOTS; ++j) {
      int o = (j * WAVES + wave) * 1024 + lane * 16;
      int g = o ^ (((o >> 7) & 7) << 4);
      int row = g >> 7, colb = g & 127;
      pA[j] = (const char*)A + ((size_t)(m0 + row) * lda) * 2 + colb;
      dA[j] = ldsc + (j * WAVES + wave) * 1024;
    }
#pragma unroll
    for (int j = 0; j < BSLOTS; ++j) {
      int o = (j * WAVES + wave) * 1024 + lane * 16;
      int g = o ^ (((o >> 7) & 7) << 4);
      int row = g >> 7, colb = g & 127;
      pB[j] = (const char*)B + ((size_t)(n0 + row) * ldb) * 2 + colb;
      dB[j] = ldsc + ABYTES + (j * WAVES + wave) * 1024;
    }

    auto STAGE = [&](int buf, int k0) {
      const int bo = buf * HALF;
#pragma unroll
      for (int j = 0; j < ASLOTS; ++j) gload_lds16(pA[j] + (size_t)k0 * 2, dA[j] + bo);
#pragma unroll
      for (int j = 0; j < BSLOTS; ++j) gload_lds16(pB[j] + (size_t)k0 * 2, dB[j] + bo);
    };

    floatx4 acc[MFR][4];
#pragma unroll
    for (int i = 0; i < MFR; ++i)
#pragma unroll
      for (int j = 0; j < 4; ++j) acc[i][j] = (floatx4){0.f, 0.f, 0.f, 0.f};

    STAGE(0, 0);
    int cur = 0;
    for (int k0 = 0; k0 < Keff; k0 += 64) {
      const int kn = k0 + 64;
      if (kn < Keff) {
        STAGE(cur ^ 1, kn);
        if constexpr (ASLOTS + BSLOTS == 4) asm volatile("s_waitcnt vmcnt(4)" ::: "memory");
        else if constexpr (ASLOTS + BSLOTS == 6) asm volatile("s_waitcnt vmcnt(6)" ::: "memory");
        else                                asm volatile("s_waitcnt vmcnt(8)" ::: "memory");
      } else {
        asm volatile("s_waitcnt vmcnt(0)" ::: "memory");
      }
      __builtin_amdgcn_s_barrier();
      __builtin_amdgcn_sched_barrier(0);

      const int bo = cur * HALF;
      bf16x8 af[2][MFR], bfv[2][4];
#pragma unroll
      for (int kk = 0; kk < 2; ++kk) {
#pragma unroll
        for (int f = 0; f < MFR; ++f) {
          int rA = ra0 + f * 16;
          int oA = rA * 128 + kk * 64 + cb0; oA ^= ((rA & 7) << 4);
          af[kk][f] = *(const bf16x8*)(ldsc + bo + oA);
        }
#pragma unroll
        for (int f = 0; f < 4; ++f) {
          int rB = rb0 + f * 16;
          int oB = rB * 128 + kk * 64 + cb0; oB ^= ((rB & 7) << 4);
          bfv[kk][f] = *(const bf16x8*)(ldsc + bo + ABYTES + oB);
        }
      }
      __builtin_amdgcn_s_setprio(1);
#pragma unroll
      for (int kk = 0; kk < 2; ++kk)
#pragma unroll
        for (int mI = 0; mI < MFR; ++mI)
#pragma unroll
          for (int nI = 0; nI < 4; ++nI)
            acc[mI][nI] = __builtin_amdgcn_mfma_f32_16x16x32_bf16(
                af[kk][mI], bfv[kk][nI], acc[mI][nI], 0, 0, 0);
      __builtin_amdgcn_s_setprio(0);

      __builtin_amdgcn_sched_barrier(0);
      __builtin_amdgcn_s_barrier();
      cur ^= 1;
    }

    const int crow0 = m0 + wm * WROWS + ((lane >> 4) * 4);
    const int ccol0 = n0 + wn * 64 + (lane & 15);
    if constexpr (EPI == 1) {
      u16* C = (u16*)Cv;
#pragma unroll
      for (int mI = 0; mI < MFR; ++mI)
#pragma unroll
        for (int r = 0; r < 4; ++r) {
          size_t ro = (size_t)(crow0 + mI * 16 + r) * ldc + ccol0;
#pragma unroll
          for (int nI = 0; nI < 4; ++nI)
            C[ro + nI * 16] = f2bf(acc[mI][nI][r] * scale);
        }
    } else if constexpr (EPI == 2) {
      u16* C = (u16*)Cv;
#pragma unroll
      for (int mI = 0; mI < MFR; ++mI)
#pragma unroll
        for (int r = 0; r < 4; ++r) {
          const int row = crow0 + mI * 16 + r;
          size_t ro = (size_t)row * ldc + ccol0;
          float ls = 0.f;
#pragma unroll
          for (int nI = 0; nI < 4; ++nI) {
            const int col = ccol0 + nI * 16;
            float pp = __expf(acc[mI][nI][r] * scale);
            if (diag && col > row) pp = 0.f;
            C[ro + nI * 16] = f2bf(pp);
            ls += pp;
          }
          ls += __shfl_xor(ls, 1); ls += __shfl_xor(ls, 2);
          ls += __shfl_xor(ls, 4); ls += __shfl_xor(ls, 8);
          if ((lane & 15) == 0) atomicAdd(&sums[row], ls);
        }
    } else {
      float* C = (float*)Cv;
#pragma unroll
      for (int mI = 0; mI < MFR; ++mI)
#pragma unroll
        for (int r = 0; r < 4; ++r) {
          const int row = crow0 + mI * 16 + r;
          float inv = 1.0f;
          if (sums) inv = 1.0f / sums[row];
          size_t ro = (size_t)row * ldc + ccol0;
#pragma unroll
          for (int nI = 0; nI < 4; ++nI)
            C[ro + nI * 16] = acc[mI][nI][r] * inv;
        }
    }
  }
}

// -------- Mt = Wk Wq^T (64 blocks) + vt = Wv^T x^T (512 blocks), XCD-chunked --------
// Mt[d2][d1] = sum_e Wkb[d2,e] Wqb[d1,e]; vt[e][s] = sum_d Wvt[e,d] xb[s,d].
__global__ __launch_bounds__(256) void mt_vt_kernel(const u16* __restrict__ Wqb,
                                                    const u16* __restrict__ Wkb,
                                                    const u16* __restrict__ Wvt,
                                                    const u16* __restrict__ xb,
                                                    u16* __restrict__ Mt,
                                                    u16* __restrict__ vt) {
  const int id = blockIdx.x;
  const int lin = (id & 7) * 72 + (id >> 3);         // bijective: 576 = 8*72
  const u16 *A, *B; u16* C; int m0, n0, ldc;
  if (lin < 64) {
    A = Wkb; B = Wqb; C = Mt;
    m0 = (lin >> 3) * 128; n0 = (lin & 7) * 128; ldc = 1024;
  } else {
    const int idx = lin - 64;                        // [0,512)
    A = Wvt; B = xb; C = vt;
    m0 = (idx & 7) * 128; n0 = (idx >> 3) * 128; ldc = 8192;
  }
  gemm_core<1, 128, 4>(A, B, C, n0, 1024, 1024, ldc, 1.0f, nullptr, 0,
                       1, m0, 1024, 0, 0);
}

// -------- y = xb Mt^T : [8192 x 1024], 512 blocks, XCD-chunked --------
// y[s,e'] = sum_d xb[s,d] Mt[e',d]  (Mt[e',d] = (Wq Wk^T)[d,e'])
__global__ __launch_bounds__(256) void proj_y(const u16* __restrict__ xb,
                                              const u16* __restrict__ Mt,
                                              u16* __restrict__ y) {
  const int id = blockIdx.x;
  const int lin = (id & 7) * 64 + (id >> 3);         // bijective: 512 = 8*64
  const int bx = lin & 7, by = lin >> 3;             // 8 n-tiles, 64 m-tiles
  gemm_core<1, 128, 4>(xb, Mt, y, bx * 128, 1024, 1024, 1024, 1.0f, nullptr, 0,
                       1, by * 128, 1024, 0, 0);
}

// ---------------- scores: P~ = exp(y xb^T / 32) bf16 + atomic row sums (8-wave) ----------------
// Grid 544 = exactly the causal tiles; triangular-packed, XCD-chunked (8 x 68).
__global__ __launch_bounds__(512) void gemm_scores(const u16* __restrict__ y,
                                                   const u16* __restrict__ xb,
                                                   u16* __restrict__ sc16,
                                                   float* __restrict__ sums) {
  const int lin = blockIdx.x;
  const int g = (lin & 7) * 68 + (lin >> 3);         // bijective: 544 = 8*68
  const int z = g / 136, t = g - z * 136;
  int bi = (int)((sqrtf(8.f * (float)t + 1.f) - 1.f) * 0.5f);
  while ((bi + 1) * (bi + 2) / 2 <= t) ++bi;
  while (bi * (bi + 1) / 2 > t) --bi;
  const int bj = t - bi * (bi + 1) / 2;
  gemm_core<2, 128, 8>(y + (size_t)z * 2097152, xb + (size_t)z * 2097152,
                       sc16 + (size_t)z * 4194304,
                       bj * 128, 1024, 1024, 2048, 0.03125f,
                       sums + z * 2048, (bi == bj) ? 1 : 0,
                       1, bi * 128, 1024, 0, 0);
}

// ---------------- PV paired (8-wave): block does tiles bi=15-y THEN bi=y ----------------
__global__ __launch_bounds__(512) void gemm_pv(const u16* __restrict__ sc16,
                                               const u16* __restrict__ vt,
                                               float* __restrict__ out,
                                               float* __restrict__ sums) {
  const int bj = blockIdx.x, z = blockIdx.z, yb = blockIdx.y;  // yb in [0,8)
  const int bi1 = 15 - yb, bi2 = yb;                           // big first
  gemm_core<3, 128, 8>(sc16 + (size_t)z * 4194304, vt + (size_t)z * 2048,
                       out + (size_t)z * 2097152,
                       bj * 128, 2048, 8192, 1024, 1.0f,
                       sums + z * 2048, 0,
                       2, bi1 * 128, (bi1 + 1) * 128, bi2 * 128, (bi2 + 1) * 128);
}

// ---------------- launch ----------------
extern "C" void kernel_launch(void* const* d_in, const int* in_sizes, int n_in,
                              void* d_out, int out_size, void* d_ws, size_t ws_size,
                              hipStream_t stream) {
  const float* x  = (const float*)d_in[0];
  const float* Wq = (const float*)d_in[1];
  const float* Wk = (const float*)d_in[2];
  const float* Wv = (const float*)d_in[3];
  float* out = (float*)d_out;
  char* ws = (char*)d_ws;

  const size_t MB = 1ull << 20;
  u16*  xb   = (u16*)(ws);              // 16 MiB : x bf16           [8192][1024]
  u16*  Wvt  = (u16*)(ws + 16 * MB);    //  2 MiB : Wv^T bf16        [1024][1024]
  u16*  Wqb  = (u16*)(ws + 18 * MB);    //  2 MiB : Wq bf16          [1024][1024]
  u16*  Wkb  = (u16*)(ws + 20 * MB);    //  2 MiB : Wk bf16          [1024][1024]
  u16*  Mt   = (u16*)(ws + 22 * MB);    //  2 MiB : (Wk Wq^T) bf16   [1024][1024]
  u16*  y    = (u16*)(ws + 24 * MB);    // 16 MiB : x (WqWk^T) bf16  [8192][1024]
  u16*  vt   = (u16*)(ws + 40 * MB);    // 16 MiB : v^T bf16         [1024][8192]
  u16*  sc16 = (u16*)(ws + 56 * MB);    // 32 MiB : P~ bf16          [4][2048][2048]
  float* sums = (float*)(ws + 88 * MB); // 32 KiB : row sums         [4][2048]

  // xb + Wq/Wk casts + Wv transpose + sums=0
  prep_kernel<<<11296, 256, 0, stream>>>((const float4*)x, xb, Wq, Wk, Wv,
                                         Wqb, Wkb, Wvt, sums);

  // Mt (64 blocks) + vt (512 blocks)
  mt_vt_kernel<<<576, 256, 0, stream>>>(Wqb, Wkb, Wvt, xb, Mt, vt);

  // y = xb Mt^T : 512 blocks
  proj_y<<<512, 256, 0, stream>>>(xb, Mt, y);

  // P~ = exp(y xb^T / 32) bf16 + row sums : 544 blocks x 512 threads
  gemm_scores<<<544, 512, 0, stream>>>(y, xb, sc16, sums);

  // out = P~ V / rowsum : 256 blocks x 512 threads, perfectly paired
  gemm_pv<<<dim3(8, 8, 4), 512, 0, stream>>>(sc16, vt, out, sums);
}